// Round 6
// baseline (421.761 us; speedup 1.0000x reference)
//
#include <hip/hip_runtime.h>

#define Tn 200
#define Dn 64
#define Hn 64

typedef _Float16 half8v __attribute__((ext_vector_type(8)));
typedef float    f32x4  __attribute__((ext_vector_type(4)));
typedef unsigned int uint;

__device__ __forceinline__ float fast_sigmoid(float v) {
    return __builtin_amdgcn_rcpf(1.0f + __expf(-v));
}
__device__ __forceinline__ float fast_tanh(float v) {
    return 1.0f - 2.0f * __builtin_amdgcn_rcpf(1.0f + __expf(2.0f * v));
}
__device__ __forceinline__ uint pk16(float a, float b) {
    return __builtin_bit_cast(uint, __builtin_amdgcn_cvt_pkrtz(a, b));
}

// Block-wide barrier that drains ONLY the LDS queue (lgkmcnt), never vmcnt.
// __syncthreads() would emit s_waitcnt vmcnt(0) and synchronously eat the
// ~600-900 cyc HBM latency of the in-flight X/att prefetch + store acks,
// twice per step (R4 post-mortem: this was ~2000 of the 3460 cyc/step).
// Hazard analysis (R4/R5): all cross-wave traffic through s_rh/s_hh is LDS;
// lgkmcnt(0) commits this wave's ds_writes and drains its prior ds_reads
// before arrival, so the 2-barrier scheme stays correct. Barrier counts are
// block-uniform (Lmax identical in all waves).
__device__ __forceinline__ void bar_lgkm() {
    asm volatile("s_waitcnt lgkmcnt(0)" ::: "memory");
    __builtin_amdgcn_s_barrier();
    asm volatile("" ::: "memory");   // compiler-level fence: no mem-op hoisting
}

#define MFMA16(a, b, c) __builtin_amdgcn_mfma_f32_16x16x32_f16(a, b, c, 0, 0, 0)

// ============================================================================
// Fully fused AUGRU: 16 batch rows per BLOCK, 4 waves cooperating.
// Wave w owns gate/cand columns [16w, 16w+16): 3 MFMA tiles (r,u,c) x 4 K-chunks
// = 12 MFMAs/step/wave. Swapped-operand MFMA layout (verified R3/R4):
//   A'(weights): lane holds W[k = (l>>4)*8+e][16w + (l&15)]
//   B'(state):   lane holds S[m = l&15][k = (l>>4)*8+e]
//   D'(gates):   lane holds G[col = 16w + 4*(l>>4)+reg][row m = l&15]
// Cross-wave exchange of r*h and h via 2x 2.3KB LDS transpose buffers,
// 2 lgkm-only barriers per step. x-part MFMAs issue before h-part.
// ============================================================================

#define AUGRU_STEP(q0, q1, q2, q3, af, tcur)                                    \
  {                                                                             \
    uint4 ux;                                                                   \
    ux.x = pk16(q0.x, q0.y); ux.y = pk16(q0.z, q0.w);                           \
    ux.z = pk16(q1.x, q1.y); ux.w = pk16(q1.z, q1.w);                           \
    const half8v bx0 = __builtin_bit_cast(half8v, ux);                          \
    ux.x = pk16(q2.x, q2.y); ux.y = pk16(q2.z, q2.w);                           \
    ux.z = pk16(q3.x, q3.y); ux.w = pk16(q3.z, q3.w);                           \
    const half8v bx1 = __builtin_bit_cast(half8v, ux);                          \
    const float uf = 1.0f - af;                                                 \
    { /* prefetch X/att for t+2 into the same named slot (floats across bars) */\
      const int tp = min(tcur + 2, Lmax - 1);                                   \
      if (tp < len_m) {                                                         \
        const float* xr = xb + (size_t)tp * Dn + kq * 8;                        \
        q0 = *(const float4*)(xr);      q1 = *(const float4*)(xr + 4);          \
        q2 = *(const float4*)(xr + 32); q3 = *(const float4*)(xr + 36);         \
      }                                                                         \
      af = ab[tp];                                                              \
    }                                                                           \
    f32x4 R = biasR, U = biasU, C = biasC;                                      \
    /* x-part first (independent of h) */                                       \
    R = MFMA16(Ar[0], bx0, R);  R = MFMA16(Ar[1], bx1, R);                      \
    U = MFMA16(Au[0], bx0, U);  U = MFMA16(Au[1], bx1, U);                      \
    C = MFMA16(Acn[0], bx0, C); C = MFMA16(Acn[1], bx1, C);                     \
    /* h-part (bh frags from end of previous step) */                           \
    R = MFMA16(Ar[2], bh0, R);  R = MFMA16(Ar[3], bh1, R);                      \
    U = MFMA16(Au[2], bh0, U);  U = MFMA16(Au[3], bh1, U);                      \
    s_rh[trw + 0] = pk16(fast_sigmoid(R[0]) * hs4[0],                           \
                         fast_sigmoid(R[1]) * hs4[1]);                          \
    s_rh[trw + 1] = pk16(fast_sigmoid(R[2]) * hs4[2],                           \
                         fast_sigmoid(R[3]) * hs4[3]);                          \
    /* u-path VALU runs under the LDS/barrier shadow */                         \
    const float uh0 = uf * fast_sigmoid(U[0]);                                  \
    const float uh1 = uf * fast_sigmoid(U[1]);                                  \
    const float uh2 = uf * fast_sigmoid(U[2]);                                  \
    const float uh3 = uf * fast_sigmoid(U[3]);                                  \
    bar_lgkm(); /* bar A: s_rh complete (LDS only) */                           \
    const half8v brh0 = __builtin_bit_cast(half8v,                              \
        *(const uint4*)&s_rh[trr]);                                             \
    const half8v brh1 = __builtin_bit_cast(half8v,                              \
        *(const uint4*)&s_rh[trr + 16]);                                        \
    C = MFMA16(Acn[2], brh0, C); C = MFMA16(Acn[3], brh1, C);                   \
    {                                                                           \
      const float c0 = fast_tanh(C[0]); hs4[0] = c0 + uh0 * (hs4[0] - c0);      \
      const float c1 = fast_tanh(C[1]); hs4[1] = c1 + uh1 * (hs4[1] - c1);      \
      const float c2 = fast_tanh(C[2]); hs4[2] = c2 + uh2 * (hs4[2] - c2);      \
      const float c3 = fast_tanh(C[3]); hs4[3] = c3 + uh3 * (hs4[3] - c3);      \
    }                                                                           \
    if (tcur < len_m) {                                                         \
      *(float4*)(orow + (size_t)tcur * Hn + 16 * w + 4 * kq) =                  \
          make_float4(hs4[0], hs4[1], hs4[2], hs4[3]);                          \
    }                                                                           \
    s_hh[trw + 0] = pk16(hs4[0], hs4[1]);                                       \
    s_hh[trw + 1] = pk16(hs4[2], hs4[3]);                                       \
    bar_lgkm(); /* bar B: s_hh complete (LDS only) */                           \
    bh0 = __builtin_bit_cast(half8v, *(const uint4*)&s_hh[trr]);                \
    bh1 = __builtin_bit_cast(half8v, *(const uint4*)&s_hh[trr + 16]);           \
  }

__global__ __launch_bounds__(256, 1)
void augru_fused16x4(const float* __restrict__ x,    // [B,T,64]
                     const int*   __restrict__ slen, // [B]
                     const float* __restrict__ att,  // [B,T]
                     const float* __restrict__ gk,   // [128][128]
                     const float* __restrict__ gb,   // [128]
                     const float* __restrict__ ck,   // [128][64]
                     const float* __restrict__ cb,   // [64]
                     float*       __restrict__ out,  // [B,T,64]
                     int B)
{
    const int tid  = threadIdx.x;
    const int w    = tid >> 6;      // wave id 0..3 = gate-column tile
    const int lane = tid & 63;
    const int lm   = lane & 15;     // batch row within group
    const int kq   = lane >> 4;     // K quadrant / output sub-column

    const int b0    = blockIdx.x * 16;
    const int brow  = b0 + lm;
    const int browc = min(brow, B - 1);
    const int len_m = (brow < B) ? slen[brow] : 0;

    // wave-wide max sequence length (same 16 rows in every wave)
    int Lmax = len_m;
#pragma unroll
    for (int off = 32; off; off >>= 1) Lmax = max(Lmax, __shfl_xor(Lmax, off));

    __shared__ uint s_rh[16 * 36];   // 2304 B transpose scratch (r*h)
    __shared__ uint s_hh[16 * 36];   // 2304 B transpose scratch (h)

    // LDS addressing: row m stride 36 dwords (pad spreads banks)
    const int trw = lm * 36 + 8 * w + 2 * kq;  // write base (this wave's cols)
    const int trr = lm * 36 + 4 * kq;          // read base (full-K B'-frag)

    // ---- persistent weight A'-fragments + bias C-inits for THIS wave's tile ----
    half8v Ar[4], Au[4], Acn[4];
#pragma unroll
    for (int kc = 0; kc < 4; ++kc) {
        half8v fr, fu, fc;
#pragma unroll
        for (int e = 0; e < 8; ++e) {
            const int k = kc * 32 + kq * 8 + e;
            fr[e] = (_Float16)gk[k * 128 + 16 * w + lm];
            fu[e] = (_Float16)gk[k * 128 + 64 + 16 * w + lm];
            fc[e] = (_Float16)ck[k * 64 + 16 * w + lm];
        }
        Ar[kc] = fr; Au[kc] = fu; Acn[kc] = fc;
    }
    const f32x4 biasR = {gb[16 * w + 4 * kq + 0], gb[16 * w + 4 * kq + 1],
                         gb[16 * w + 4 * kq + 2], gb[16 * w + 4 * kq + 3]};
    const f32x4 biasU = {gb[64 + 16 * w + 4 * kq + 0], gb[64 + 16 * w + 4 * kq + 1],
                         gb[64 + 16 * w + 4 * kq + 2], gb[64 + 16 * w + 4 * kq + 3]};
    const f32x4 biasC = {cb[16 * w + 4 * kq + 0], cb[16 * w + 4 * kq + 1],
                         cb[16 * w + 4 * kq + 2], cb[16 * w + 4 * kq + 3]};

    const float* xb   = x   + (size_t)browc * Tn * Dn;
    const float* ab   = att + (size_t)browc * Tn;
    float*       orow = out + (size_t)brow * Tn * Hn;   // only used if valid

    // ---- state: 4 h values per lane (row lm, cols 16w+4kq..+3) ----
    float hs4[4] = {0.f, 0.f, 0.f, 0.f};
    half8v bh0 = half8v{0}, bh1 = half8v{0};

    // ---- 2-deep named X/att prefetch slots ----
    float4 qA0{}, qA1{}, qA2{}, qA3{}, qB0{}, qB1{}, qB2{}, qB3{};
    float aA = 0.f, aB = 0.f;

    if (Lmax > 0) {
        if (0 < len_m) {
            const float* xr = xb + kq * 8;
            qA0 = *(const float4*)(xr);      qA1 = *(const float4*)(xr + 4);
            qA2 = *(const float4*)(xr + 32); qA3 = *(const float4*)(xr + 36);
        }
        aA = ab[0];
        const int t1 = min(1, Lmax - 1);
        if (t1 < len_m) {
            const float* xr = xb + (size_t)t1 * Dn + kq * 8;
            qB0 = *(const float4*)(xr);      qB1 = *(const float4*)(xr + 4);
            qB2 = *(const float4*)(xr + 32); qB3 = *(const float4*)(xr + 36);
        }
        aB = ab[t1];

        int t = 0;
        for (;;) {
            AUGRU_STEP(qA0, qA1, qA2, qA3, aA, t);
            if (++t >= Lmax) break;
            AUGRU_STEP(qB0, qB1, qB2, qB3, aB, t);
            if (++t >= Lmax) break;
        }
    }

    // ---- zero tails: out[b, len:T, :] = 0, all 256 threads per row ----
#pragma unroll 1
    for (int mm = 0; mm < 16; ++mm) {
        const int row = b0 + mm;
        if (row >= B) break;
        const int L = __shfl(len_m, mm);
        float* tail = out + ((size_t)row * Tn + L) * Hn;
        const int total = (Tn - L) * Hn;
        for (int i = tid * 4; i < total; i += 1024) {
            *(float4*)(tail + i) = make_float4(0.f, 0.f, 0.f, 0.f);
        }
    }
}

extern "C" void kernel_launch(void* const* d_in, const int* in_sizes, int n_in,
                              void* d_out, int out_size, void* d_ws, size_t ws_size,
                              hipStream_t stream) {
    const float* x    = (const float*)d_in[0];
    const int*   slen = (const int*)  d_in[1];
    const float* att  = (const float*)d_in[2];
    const float* gk   = (const float*)d_in[3];
    const float* gb   = (const float*)d_in[4];
    const float* ck   = (const float*)d_in[5];
    const float* cb   = (const float*)d_in[6];
    float* out = (float*)d_out;

    const int B = in_sizes[1];  // 2048
    const int grid = (B + 15) / 16;
    augru_fused16x4<<<grid, 256, 0, stream>>>(x, slen, att, gk, gb, ck, cb, out, B);
}

// Round 7
// 358.513 us; speedup vs baseline: 1.1764x; 1.1764x over previous
//
#include <hip/hip_runtime.h>

#define Tn 200
#define Dn 64
#define Hn 64
#define CC 16   // chunk size for fallback kernel

typedef _Float16 half2v __attribute__((ext_vector_type(2)));
typedef _Float16 half8v __attribute__((ext_vector_type(8)));
typedef float    f32x4  __attribute__((ext_vector_type(4)));

__device__ __forceinline__ float fast_sigmoid(float v) {
    return __builtin_amdgcn_rcpf(1.0f + __expf(-v));
}
__device__ __forceinline__ float fast_tanh(float v) {
    return 1.0f - 2.0f * __builtin_amdgcn_rcpf(1.0f + __expf(2.0f * v));
}

// Compiler-only fence. For a SINGLE-wave block, DS ops from the same wave are
// processed in order by hardware (CDNA DS pipe), so write->read RAW and
// read->write WAR through LDS need NO s_waitcnt between them. We only need to
// stop the COMPILER from reordering the aliasing LDS accesses; the compiler
// still inserts the minimal lgkmcnt before the first USE of each ds_read
// result (register dependency). R6 post-mortem: the old
// `s_waitcnt lgkmcnt(0)` fences (3/step) were synchronous write-commit drains
// sitting directly on the recurrence critical path.
__device__ __forceinline__ void cfence() {
    asm volatile("" ::: "memory");
}
// Full fence for the multi-wave fallback kernel (cross-wave LDS ordering).
__device__ __forceinline__ void wave_lds_fence() {
    asm volatile("s_waitcnt lgkmcnt(0)" ::: "memory");
}

__device__ __forceinline__ half8v cvt8(const float4 a, const float4 b) {
    return half8v{(_Float16)a.x, (_Float16)a.y, (_Float16)a.z, (_Float16)a.w,
                  (_Float16)b.x, (_Float16)b.y, (_Float16)b.z, (_Float16)b.w};
}

// ============================================================================
// Kernel 1: x-projection as an MFMA GEMM over flat rows. (verified R1 form)
// ============================================================================
__global__ __launch_bounds__(256, 4)
void augru_proj_mfma(const float* __restrict__ x,     // [B*T, 64]
                     const int*   __restrict__ slen,  // [B]
                     const float* __restrict__ gk,    // [128][128]
                     const float* __restrict__ gb,    // [128]
                     const float* __restrict__ ck,    // [128][64]
                     const float* __restrict__ cb,    // [64]
                     _Float16*    __restrict__ P,     // [B*T, 192] fp16
                     int nrows, int nchunks)
{
    const int tid  = threadIdx.x;
    const int w    = tid >> 6;      // wave id 0..3
    const int lane = tid & 63;
    const int lm   = lane & 15;     // M (A) / N (B,C) index inside fragment
    const int kq   = lane >> 4;     // K quadrant

    half8v bf[3][2];
    float  bias[3];
#pragma unroll
    for (int nt = 0; nt < 3; ++nt) {
        const int n = w * 48 + nt * 16 + lm;
#pragma unroll
        for (int kh = 0; kh < 2; ++kh) {
            const int kb = kh * 32 + kq * 8;
            half8v f;
#pragma unroll
            for (int e = 0; e < 8; ++e) {
                const int k = kb + e;
                const float v = (n < 128) ? gk[k * 128 + n]
                                          : ck[k * 64 + (n - 128)];
                f[e] = (_Float16)v;
            }
            bf[nt][kh] = f;
        }
        bias[nt] = (n < 128) ? gb[n] : cb[n - 128];
    }

    for (int chunk = blockIdx.x; chunk < nchunks; chunk += gridDim.x) {
        const int rb0 = chunk * 64;
#pragma unroll
        for (int sub = 0; sub < 4; ++sub) {
            const int rb = rb0 + sub * 16;

            const int rowv = rb + lm;
            const int bv   = rowv / Tn;
            const int tv   = rowv - bv * Tn;
            const bool v   = (rowv < nrows) && (tv < slen[bv]);
            if (__ballot(v) == 0ull) continue;   // whole subtile past seq len

            const int rowA = min(rb + lm, nrows - 1);
            const float* xr = x + (size_t)rowA * Dn + kq * 8;
            const float4 q0 = *(const float4*)(xr);
            const float4 q1 = *(const float4*)(xr + 4);
            const float4 q2 = *(const float4*)(xr + 32);
            const float4 q3 = *(const float4*)(xr + 36);
            const half8v a0 = cvt8(q0, q1);   // k = 0..31 slice
            const half8v a1 = cvt8(q2, q3);   // k = 32..63 slice

            f32x4 acc[3];
#pragma unroll
            for (int nt = 0; nt < 3; ++nt) {
                f32x4 c = {bias[nt], bias[nt], bias[nt], bias[nt]};
                c = __builtin_amdgcn_mfma_f32_16x16x32_f16(a0, bf[nt][0], c, 0, 0, 0);
                c = __builtin_amdgcn_mfma_f32_16x16x32_f16(a1, bf[nt][1], c, 0, 0, 0);
                acc[nt] = c;
            }

#pragma unroll
            for (int r = 0; r < 4; ++r) {
                const int row = rb + kq * 4 + r;
                const int bb  = row / Tn;
                const int tt  = row - bb * Tn;
                if (row < nrows && tt < slen[bb]) {
                    _Float16* Pt = P + (size_t)row * 192 + w * 48 + lm;
                    Pt[0]  = (_Float16)acc[0][r];
                    Pt[16] = (_Float16)acc[1][r];
                    Pt[32] = (_Float16)acc[2][r];
                }
            }
        }
    }
}

// ============================================================================
// Kernel 2: recurrence, 1 wave per row (R1 structure). ONLY change vs R1:
// the 3 per-step `s_waitcnt lgkmcnt(0)` fences are now compiler-only fences
// (hardware DS in-order within a wave provides the RAW/WAR ordering).
// ============================================================================
__global__ __launch_bounds__(64, 2)
void augru_rec(const _Float16* __restrict__ P,   // [B,T,3,64] fp16
               const int*     __restrict__ slen, // [B]
               const float*   __restrict__ att,  // [B,T]
               const float*   __restrict__ gk,   // [128][128]
               const float*   __restrict__ ck,   // [128][64]
               float*         __restrict__ out)  // [B,T,H]
{
    const int b = blockIdx.x;
    const int j = threadIdx.x;

    __shared__ __align__(16) _Float16 s_h[Hn];
    __shared__ __align__(16) _Float16 s_rh[Hn];

    half2v wr[32], wu[32], wc[32];   // h-part weight cols (K rows 64..127)
#pragma unroll
    for (int m = 0; m < 32; ++m) {
        const int k = 64 + 2 * m;
        wr[m] = half2v{(_Float16)gk[(k + 0) * 128 + j],
                       (_Float16)gk[(k + 1) * 128 + j]};
        wu[m] = half2v{(_Float16)gk[(k + 0) * 128 + 64 + j],
                       (_Float16)gk[(k + 1) * 128 + 64 + j]};
        wc[m] = half2v{(_Float16)ck[(k + 0) * 64 + j],
                       (_Float16)ck[(k + 1) * 64 + j]};
    }

    const int len = slen[b];
    const _Float16* Prow = P   + (size_t)b * Tn * 192;
    const float*    arow = att + (size_t)b * Tn;
    float*          orow = out + (size_t)b * Tn * Hn;

    float h = 0.0f;

    _Float16 pr_n = (_Float16)0, pu_n = (_Float16)0, pc_n = (_Float16)0;
    float a_n = 0.0f;
    if (len > 0) {
        pr_n = Prow[j]; pu_n = Prow[64 + j]; pc_n = Prow[128 + j];
        a_n  = arow[0];
    }

    for (int t = 0; t < len; ++t) {
        const float pr = (float)pr_n;    // loaded last iteration
        const float pu = (float)pu_n;
        const float pc = (float)pc_n;
        const float a  = a_n;
        const int tn = min(t + 1, len - 1);
        const _Float16* Pt = Prow + (size_t)tn * 192;
        pr_n = Pt[j]; pu_n = Pt[64 + j]; pc_n = Pt[128 + j];
        a_n  = arow[tn];

        s_h[j] = (_Float16)h;
        cfence();   // order only; HW DS pipe is in-order within the wave

        float r0 = pr, r1 = 0.f, u0 = pu, u1 = 0.f;
        const half8v* hv = (const half8v*)s_h;   // 8 x 16B broadcast reads
#pragma unroll
        for (int m8 = 0; m8 < 8; ++m8) {
            const half8v v = hv[m8];
            const half2v p0 = __builtin_shufflevector(v, v, 0, 1);
            const half2v p1 = __builtin_shufflevector(v, v, 2, 3);
            const half2v p2 = __builtin_shufflevector(v, v, 4, 5);
            const half2v p3 = __builtin_shufflevector(v, v, 6, 7);
            const int m = m8 * 4;
            r0 = __builtin_amdgcn_fdot2(p0, wr[m + 0], r0, false);
            r1 = __builtin_amdgcn_fdot2(p1, wr[m + 1], r1, false);
            r0 = __builtin_amdgcn_fdot2(p2, wr[m + 2], r0, false);
            r1 = __builtin_amdgcn_fdot2(p3, wr[m + 3], r1, false);
            u0 = __builtin_amdgcn_fdot2(p0, wu[m + 0], u0, false);
            u1 = __builtin_amdgcn_fdot2(p1, wu[m + 1], u1, false);
            u0 = __builtin_amdgcn_fdot2(p2, wu[m + 2], u0, false);
            u1 = __builtin_amdgcn_fdot2(p3, wu[m + 3], u1, false);
        }
        const float rg = fast_sigmoid(r0 + r1);
        const float ug = fast_sigmoid(u0 + u1);

        s_rh[j] = (_Float16)(rg * h);
        cfence();

        float c0 = pc, c1 = 0.f;
        const half8v* rv = (const half8v*)s_rh;
#pragma unroll
        for (int m8 = 0; m8 < 8; ++m8) {
            const half8v v = rv[m8];
            const half2v p0 = __builtin_shufflevector(v, v, 0, 1);
            const half2v p1 = __builtin_shufflevector(v, v, 2, 3);
            const half2v p2 = __builtin_shufflevector(v, v, 4, 5);
            const half2v p3 = __builtin_shufflevector(v, v, 6, 7);
            const int m = m8 * 4;
            c0 = __builtin_amdgcn_fdot2(p0, wc[m + 0], c0, false);
            c1 = __builtin_amdgcn_fdot2(p1, wc[m + 1], c1, false);
            c0 = __builtin_amdgcn_fdot2(p2, wc[m + 2], c0, false);
            c1 = __builtin_amdgcn_fdot2(p3, wc[m + 3], c1, false);
        }
        const float cg = fast_tanh(c0 + c1);

        const float uh = (1.0f - a) * ug;
        h = uh * h + (1.0f - uh) * cg;
        orow[t * Hn + j] = h;
        cfence();   // WAR vs next t's s_h/s_rh writes: HW in-order, compiler pinned
    }

    // ---- zero tail: out[b, len:T, :] = 0 ----
    float4 z;
    z.x = z.y = z.z = z.w = 0.0f;
    float* tail = orow + (size_t)len * Hn;
    const int total = (Tn - len) * Hn;
    for (int i = j * 4; i < total; i += 64 * 4) {
        *(float4*)(tail + i) = z;
    }
}

// ============================================================================
// Fallback (fused, ~430 us) if ws is too small for P. (unchanged)
// ============================================================================
__global__ __launch_bounds__(128, 2)
void augru_fused_fb(const float* __restrict__ x, const int* __restrict__ slen,
                    const float* __restrict__ att, const float* __restrict__ gk,
                    const float* __restrict__ gb, const float* __restrict__ ck,
                    const float* __restrict__ cb, float* __restrict__ out)
{
    const int b    = blockIdx.x;
    const int tid  = threadIdx.x;
    const int wave = tid >> 6;
    const int j    = tid & 63;

    __shared__ float s_P[2][CC][3][Hn];
    __shared__ __align__(16) _Float16 s_h[Hn];
    __shared__ __align__(16) _Float16 s_rh[Hn];

    const int len     = slen[b];
    const int nchunks = (len + CC - 1) / CC;
    const float* xrow = x   + (size_t)b * Tn * Dn;
    const float* arow = att + (size_t)b * Tn;
    float*       orow = out + (size_t)b * Tn * Hn;

    if (wave == 0) {
        half2v wr[32], wu[32], wc[32];
#pragma unroll
        for (int m = 0; m < 32; ++m) {
            const int k = 2 * m;
            wr[m] = half2v{(_Float16)gk[(k + 0) * 128 + j], (_Float16)gk[(k + 1) * 128 + j]};
            wu[m] = half2v{(_Float16)gk[(k + 0) * 128 + 64 + j], (_Float16)gk[(k + 1) * 128 + 64 + j]};
            wc[m] = half2v{(_Float16)ck[(k + 0) * 64 + j], (_Float16)ck[(k + 1) * 64 + j]};
        }
        const float br = gb[j], bu = gb[64 + j], bc = cb[j];
        for (int c = 0; c < nchunks; ++c) {
            const int t0 = c * CC, tend = min(len, t0 + CC);
            for (int t = t0; t < tend; ++t) {
                const float4* xv = (const float4*)(xrow + t * Dn);
                float r0 = br, r1 = 0.f, u0 = bu, u1 = 0.f, c0 = bc, c1 = 0.f;
#pragma unroll
                for (int kk = 0; kk < 16; ++kk) {
                    const float4 q = xv[kk];
                    const half2v p0 = half2v{(_Float16)q.x, (_Float16)q.y};
                    const half2v p1 = half2v{(_Float16)q.z, (_Float16)q.w};
                    const int m = 2 * kk;
                    r0 = __builtin_amdgcn_fdot2(p0, wr[m], r0, false);
                    r1 = __builtin_amdgcn_fdot2(p1, wr[m + 1], r1, false);
                    u0 = __builtin_amdgcn_fdot2(p0, wu[m], u0, false);
                    u1 = __builtin_amdgcn_fdot2(p1, wu[m + 1], u1, false);
                    c0 = __builtin_amdgcn_fdot2(p0, wc[m], c0, false);
                    c1 = __builtin_amdgcn_fdot2(p1, wc[m + 1], c1, false);
                }
                const int lt = t - t0;
                s_P[c & 1][lt][0][j] = r0 + r1;
                s_P[c & 1][lt][1][j] = u0 + u1;
                s_P[c & 1][lt][2][j] = c0 + c1;
            }
            __syncthreads();
        }
    } else {
        half2v wr[32], wu[32], wc[32];
#pragma unroll
        for (int m = 0; m < 32; ++m) {
            const int k = 64 + 2 * m;
            wr[m] = half2v{(_Float16)gk[(k + 0) * 128 + j], (_Float16)gk[(k + 1) * 128 + j]};
            wu[m] = half2v{(_Float16)gk[(k + 0) * 128 + 64 + j], (_Float16)gk[(k + 1) * 128 + 64 + j]};
            wc[m] = half2v{(_Float16)ck[(k + 0) * 64 + j], (_Float16)ck[(k + 1) * 64 + j]};
        }
        float h = 0.0f;
        for (int c = 0; c < nchunks; ++c) {
            __syncthreads();
            const int t0 = c * CC, tend = min(len, t0 + CC);
            for (int t = t0; t < tend; ++t) {
                const int lt = t - t0;
                const float pr = s_P[c & 1][lt][0][j];
                const float pu = s_P[c & 1][lt][1][j];
                const float pc = s_P[c & 1][lt][2][j];
                const float a  = arow[t];
                s_h[j] = (_Float16)h;
                wave_lds_fence();
                float r0 = pr, r1 = 0.f, u0 = pu, u1 = 0.f;
                const half8v* hv = (const half8v*)s_h;
#pragma unroll
                for (int m8 = 0; m8 < 8; ++m8) {
                    const half8v v = hv[m8];
                    const half2v p0 = __builtin_shufflevector(v, v, 0, 1);
                    const half2v p1 = __builtin_shufflevector(v, v, 2, 3);
                    const half2v p2 = __builtin_shufflevector(v, v, 4, 5);
                    const half2v p3 = __builtin_shufflevector(v, v, 6, 7);
                    const int m = m8 * 4;
                    r0 = __builtin_amdgcn_fdot2(p0, wr[m + 0], r0, false);
                    r1 = __builtin_amdgcn_fdot2(p1, wr[m + 1], r1, false);
                    r0 = __builtin_amdgcn_fdot2(p2, wr[m + 2], r0, false);
                    r1 = __builtin_amdgcn_fdot2(p3, wr[m + 3], r1, false);
                    u0 = __builtin_amdgcn_fdot2(p0, wu[m + 0], u0, false);
                    u1 = __builtin_amdgcn_fdot2(p1, wu[m + 1], u1, false);
                    u0 = __builtin_amdgcn_fdot2(p2, wu[m + 2], u0, false);
                    u1 = __builtin_amdgcn_fdot2(p3, wu[m + 3], u1, false);
                }
                const float rg = fast_sigmoid(r0 + r1);
                const float ug = fast_sigmoid(u0 + u1);
                s_rh[j] = (_Float16)(rg * h);
                wave_lds_fence();
                float c0 = pc, c1 = 0.f;
                const half8v* rv = (const half8v*)s_rh;
#pragma unroll
                for (int m8 = 0; m8 < 8; ++m8) {
                    const half8v v = rv[m8];
                    const half2v p0 = __builtin_shufflevector(v, v, 0, 1);
                    const half2v p1 = __builtin_shufflevector(v, v, 2, 3);
                    const half2v p2 = __builtin_shufflevector(v, v, 4, 5);
                    const half2v p3 = __builtin_shufflevector(v, v, 6, 7);
                    const int m = m8 * 4;
                    c0 = __builtin_amdgcn_fdot2(p0, wc[m + 0], c0, false);
                    c1 = __builtin_amdgcn_fdot2(p1, wc[m + 1], c1, false);
                    c0 = __builtin_amdgcn_fdot2(p2, wc[m + 2], c0, false);
                    c1 = __builtin_amdgcn_fdot2(p3, wc[m + 3], c1, false);
                }
                const float cg = fast_tanh(c0 + c1);
                const float uh = (1.0f - a) * ug;
                h = uh * h + (1.0f - uh) * cg;
                orow[t * Hn + j] = h;
                wave_lds_fence();
            }
        }
    }
    float4 z; z.x = z.y = z.z = z.w = 0.0f;
    float* tail = orow + len * Hn;
    const int total = (Tn - len) * Hn;
    for (int i = tid * 4; i < total; i += 128 * 4) *(float4*)(tail + i) = z;
}

extern "C" void kernel_launch(void* const* d_in, const int* in_sizes, int n_in,
                              void* d_out, int out_size, void* d_ws, size_t ws_size,
                              hipStream_t stream) {
    const float* x    = (const float*)d_in[0];
    const int*   slen = (const int*)  d_in[1];
    const float* att  = (const float*)d_in[2];
    const float* gk   = (const float*)d_in[3];
    const float* gb   = (const float*)d_in[4];
    const float* ck   = (const float*)d_in[5];
    const float* cb   = (const float*)d_in[6];
    float* out = (float*)d_out;

    const int B = in_sizes[1];  // 2048
    const size_t needP = (size_t)B * Tn * 192 * sizeof(_Float16);  // 157 MB

    if (ws_size >= needP) {
        _Float16* P = (_Float16*)d_ws;
        const int nrows   = B * Tn;
        const int nchunks = (nrows + 63) / 64;
        const int grid    = nchunks < 1024 ? nchunks : 1024;
        augru_proj_mfma<<<grid, 256, 0, stream>>>(x, slen, gk, gb, ck, cb, P,
                                                  nrows, nchunks);
        augru_rec<<<B, 64, 0, stream>>>(P, slen, att, gk, ck, out);
    } else {
        augru_fused_fb<<<B, 128, 0, stream>>>(x, slen, att, gk, gb, ck, cb, out);
    }
}